// Round 4
// baseline (130.558 us; speedup 1.0000x reference)
//
#include <hip/hip_runtime.h>
#include <cmath>
#include <complex>
#include <cstring>
#include <algorithm>

typedef float f32x4 __attribute__((ext_vector_type(4)));

// ---------------- CG coefficient pack (computed on host, passed by value) ----

struct CGPack {
  float A0;          // (1,1,1) path 0x0->0
  float B[3][3];     // (1,3,3) -> [j][k]   0x1->1
  float C[5][5];     // (1,5,5) -> [j][k]   0x2->2
  float D[3][3];     // (3,1,3) -> [i][k]   1x0->1
  float E[3][3];     // (3,3,1) -> [i][j]   1x1->0
  float F[3][3][5];  // (3,3,5)             1x1->2
  float G[3][5][3];  // (3,5,3)             1x2->1
  float H[5][5];     // (5,1,5) -> [i][k]   2x0->2
  float I[5][3][3];  // (5,3,3)             2x1->1
  float J[5][5];     // (5,5,1) -> [i][j]   2x2->0
  float K[5][5][5];  // (5,5,5)             2x2->2
};

namespace {

using cd = std::complex<double>;

double factd(int n) { double r = 1.0; for (int i = 2; i <= n; ++i) r *= i; return r; }

double su2_cg(int j1, int m1, int j2, int m2, int j3, int m3) {
  if (m3 != m1 + m2) return 0.0;
  int vmin = std::max(std::max(-j1 + j2 + m3, -j1 + m1), 0);
  int vmax = std::min(std::min(j2 + j3 + m1, j3 - j1 + j2), j3 + m3);
  double C = std::sqrt((2.0 * j3 + 1.0) *
      factd(j3 + j1 - j2) * factd(j3 - j1 + j2) * factd(j1 + j2 - j3) *
      factd(j3 + m3) * factd(j3 - m3) /
      (factd(j1 + j2 + j3 + 1) * factd(j1 - m1) * factd(j1 + m1) *
       factd(j2 - m2) * factd(j2 + m2)));
  double S = 0.0;
  for (int v = vmin; v <= vmax; ++v) {
    double sgn = ((v + j2 + m2) & 1) ? -1.0 : 1.0;
    S += sgn * factd(j2 + j3 + m1 - v) * factd(j1 - m1 + v) /
         (factd(v) * factd(j3 - j1 + j2 - v) * factd(j3 + m3 - v) *
          factd(v + j1 - j2 - m3));
  }
  return C * S;
}

void real_to_complex(int l, cd q[5][5]) {
  for (int r = 0; r < 5; ++r)
    for (int c = 0; c < 5; ++c) q[r][c] = cd(0.0, 0.0);
  const double is2 = 1.0 / std::sqrt(2.0);
  for (int m = -l; m < 0; ++m) {
    q[l + m][l - m] = cd(is2, 0.0);   // col l+|m|
    q[l + m][l + m] = cd(0.0, -is2);  // col l-|m|
  }
  q[l][l] = cd(1.0, 0.0);
  for (int m = 1; m <= l; ++m) {
    double s = (m & 1) ? -1.0 : 1.0;
    q[l + m][l + m] = cd(s * is2, 0.0);
    q[l + m][l - m] = cd(0.0, s * is2);
  }
  cd f(1.0, 0.0);
  const cd mi(0.0, -1.0);
  for (int t = 0; t < l; ++t) f *= mi;
  for (int r = 0; r < 5; ++r)
    for (int c = 0; c < 5; ++c) q[r][c] *= f;
}

// dense real CG with component norm (== reference clebsch_gordan * sqrt(2*l3+1))
void compute_cg(int l1, int l2, int l3, float* out) {
  const int n1 = 2 * l1 + 1, n2 = 2 * l2 + 1, n3 = 2 * l3 + 1;
  double su2[5][5][5] = {};
  if (std::abs(l1 - l2) <= l3 && l3 <= l1 + l2) {
    for (int m1 = -l1; m1 <= l1; ++m1)
      for (int m2 = -l2; m2 <= l2; ++m2)
        if (std::abs(m1 + m2) <= l3)
          su2[l1 + m1][l2 + m2][l3 + m1 + m2] = su2_cg(l1, m1, l2, m2, l3, m1 + m2);
  }
  const double norm = 1.0 / std::sqrt(2.0 * l3 + 1.0);       // from _su2_cg_mat
  const double comp = std::sqrt(2.0 * l3 + 1.0);             // component norm
  cd q1[5][5], q2[5][5], q3[5][5];
  real_to_complex(l1, q1);
  real_to_complex(l2, q2);
  real_to_complex(l3, q3);
  for (int j = 0; j < n1; ++j)
    for (int ll = 0; ll < n2; ++ll)
      for (int m = 0; m < n3; ++m) {
        cd acc(0.0, 0.0);
        for (int i = 0; i < n1; ++i)
          for (int k = 0; k < n2; ++k)
            for (int n = 0; n < n3; ++n)
              acc += q1[i][j] * q2[k][ll] * std::conj(q3[n][m]) * su2[i][k][n];
        out[(j * n2 + ll) * n3 + m] = (float)(acc.real() * norm * comp);
      }
}

CGPack make_pack() {
  CGPack p;
  float t[125];
  compute_cg(0, 0, 0, t); p.A0 = t[0];
  compute_cg(0, 1, 1, t); std::memcpy(p.B, t, 9 * sizeof(float));
  compute_cg(0, 2, 2, t); std::memcpy(p.C, t, 25 * sizeof(float));
  compute_cg(1, 0, 1, t); std::memcpy(p.D, t, 9 * sizeof(float));
  compute_cg(1, 1, 0, t); std::memcpy(p.E, t, 9 * sizeof(float));
  compute_cg(1, 1, 2, t); std::memcpy(p.F, t, 45 * sizeof(float));
  compute_cg(1, 2, 1, t); std::memcpy(p.G, t, 45 * sizeof(float));
  compute_cg(2, 0, 2, t); std::memcpy(p.H, t, 25 * sizeof(float));
  compute_cg(2, 1, 1, t); std::memcpy(p.I, t, 45 * sizeof(float));
  compute_cg(2, 2, 0, t); std::memcpy(p.J, t, 25 * sizeof(float));
  compute_cg(2, 2, 2, t); std::memcpy(p.K, t, 125 * sizeof(float));
  return p;
}

}  // namespace

// ---------------- kernel ------------------------------------------------------
//
// Block = 256 threads = 2 batch rows (128 u-channels each).
// Two store phases so LDS only holds half a row-pair at a time:
//   phase A: l3 in {0,1} chunks -> 1920 floats/row  (offsets 0..1919)
//   phase B: l3 == 2 chunks     -> 2560 floats/row  (offsets 1920..4479)
// LDS = 2 * 2560 * 4 = 20480 B -> 8 blocks/CU; launch_bounds(256,8) targets
// <=64 VGPR so occupancy is LDS/wave-slot limited at 32 waves/CU.

__global__ __launch_bounds__(256, 8) void tp_kernel(
    const float* __restrict__ in1, const float* __restrict__ in2,
    float* __restrict__ out, CGPack cg, int Btot) {
  __shared__ float smem[5120];  // max(2*1920, 2*2560) floats

  const int t = threadIdx.x;
  const int row = t >> 7;   // 0 or 1
  const int u = t & 127;
  const long long b = (long long)blockIdx.x * 2 + row;
  const bool live = (b < Btot);

  float a0 = 0.f, b0 = 0.f;
  float a1[3] = {}, a2[5] = {}, b1[3] = {}, b2[5] = {};

  if (live) {
    const float* r1 = in1 + (size_t)b * 1152;
    const float* r2 = in2 + (size_t)b * 9;
    a0 = r1[u];
#pragma unroll
    for (int i = 0; i < 3; ++i) a1[i] = r1[128 + 3 * u + i];
#pragma unroll
    for (int i = 0; i < 5; ++i) a2[i] = r1[512 + 5 * u + i];
    b0 = r2[0];
#pragma unroll
    for (int j = 0; j < 3; ++j) b1[j] = r2[1 + j];
#pragma unroll
    for (int j = 0; j < 5; ++j) b2[j] = r2[4 + j];
  }

  const long long rows_left = (long long)Btot - (long long)blockIdx.x * 2;
  const int nrows = rows_left >= 2 ? 2 : (rows_left == 1 ? 1 : 0);
  float* const orow0 = out + (size_t)blockIdx.x * 2 * 4480;

  // ================= phase A: l3 = 0 and l3 = 1 chunks =================
  {
    float* so = smem + row * 1920;

    float oA = a0 * b0 * cg.A0;
    float oE = 0.f, oJ = 0.f;
#pragma unroll
    for (int i = 0; i < 3; ++i)
#pragma unroll
      for (int j = 0; j < 3; ++j) oE += a1[i] * b1[j] * cg.E[i][j];
#pragma unroll
    for (int i = 0; i < 5; ++i)
#pragma unroll
      for (int j = 0; j < 5; ++j) oJ += a2[i] * b2[j] * cg.J[i][j];

    float oB[3] = {}, oD[3] = {}, oG[3] = {}, oI[3] = {};
#pragma unroll
    for (int j = 0; j < 3; ++j)
#pragma unroll
      for (int k = 0; k < 3; ++k) oB[k] += a0 * b1[j] * cg.B[j][k];
#pragma unroll
    for (int i = 0; i < 3; ++i)
#pragma unroll
      for (int k = 0; k < 3; ++k) oD[k] += a1[i] * b0 * cg.D[i][k];
#pragma unroll
    for (int i = 0; i < 3; ++i)
#pragma unroll
      for (int j = 0; j < 5; ++j) {
        const float p = a1[i] * b2[j];
#pragma unroll
        for (int k = 0; k < 3; ++k) oG[k] += p * cg.G[i][j][k];
      }
#pragma unroll
    for (int i = 0; i < 5; ++i)
#pragma unroll
      for (int j = 0; j < 3; ++j) {
        const float p = a2[i] * b1[j];
#pragma unroll
        for (int k = 0; k < 3; ++k) oI[k] += p * cg.I[i][j][k];
      }

    so[u] = oA;
    so[128 + u] = oE;
    so[256 + u] = oJ;
#pragma unroll
    for (int k = 0; k < 3; ++k) {
      so[384 + 3 * u + k] = oB[k];
      so[768 + 3 * u + k] = oD[k];
      so[1152 + 3 * u + k] = oG[k];
      so[1536 + 3 * u + k] = oI[k];
    }
  }

  __syncthreads();

  // store phase A: per-row contiguous 480 f32x4, nt
  {
    const int nvec = nrows * 480;
    for (int i = t; i < nvec; i += 256) {
      const int r = (i >= 480);
      const int idx = i - r * 480;
      const f32x4 v = reinterpret_cast<const f32x4*>(smem + r * 1920)[idx];
      f32x4* dst = reinterpret_cast<f32x4*>(orow0 + (size_t)r * 4480);
      __builtin_nontemporal_store(v, dst + idx);
    }
  }

  __syncthreads();

  // ================= phase B: l3 = 2 chunks =================
  {
    float* so = smem + row * 2560;

    float oC[5] = {}, oF[5] = {}, oH[5] = {}, oK[5] = {};
#pragma unroll
    for (int j = 0; j < 5; ++j)
#pragma unroll
      for (int k = 0; k < 5; ++k) oC[k] += a0 * b2[j] * cg.C[j][k];
#pragma unroll
    for (int i = 0; i < 3; ++i)
#pragma unroll
      for (int j = 0; j < 3; ++j) {
        const float p = a1[i] * b1[j];
#pragma unroll
        for (int k = 0; k < 5; ++k) oF[k] += p * cg.F[i][j][k];
      }
#pragma unroll
    for (int i = 0; i < 5; ++i)
#pragma unroll
      for (int k = 0; k < 5; ++k) oH[k] += a2[i] * b0 * cg.H[i][k];
#pragma unroll
    for (int i = 0; i < 5; ++i)
#pragma unroll
      for (int j = 0; j < 5; ++j) {
        const float p = a2[i] * b2[j];
#pragma unroll
        for (int k = 0; k < 5; ++k) oK[k] += p * cg.K[i][j][k];
      }

#pragma unroll
    for (int k = 0; k < 5; ++k) {
      so[5 * u + k] = oC[k];
      so[640 + 5 * u + k] = oF[k];
      so[1280 + 5 * u + k] = oH[k];
      so[1920 + 5 * u + k] = oK[k];
    }
  }

  __syncthreads();

  // store phase B: per-row contiguous 640 f32x4 at row offset 1920, nt
  {
    const int nvec = nrows * 640;
    for (int i = t; i < nvec; i += 256) {
      const int r = (i >= 640);
      const int idx = i - r * 640;
      const f32x4 v = reinterpret_cast<const f32x4*>(smem + r * 2560)[idx];
      f32x4* dst = reinterpret_cast<f32x4*>(orow0 + (size_t)r * 4480 + 1920);
      __builtin_nontemporal_store(v, dst + idx);
    }
  }
}

// ---------------- launch ------------------------------------------------------

extern "C" void kernel_launch(void* const* d_in, const int* in_sizes, int n_in,
                              void* d_out, int out_size, void* d_ws, size_t ws_size,
                              hipStream_t stream) {
  const float* in1 = (const float*)d_in[0];
  const float* in2 = (const float*)d_in[1];
  float* out = (float*)d_out;

  const CGPack pack = make_pack();  // pure host math, deterministic, capture-safe

  const int B = in_sizes[0] / 1152;  // 16384
  const int blocks = (B + 1) / 2;

  hipLaunchKernelGGL(tp_kernel, dim3(blocks), dim3(256), 0, stream,
                     in1, in2, out, pack, B);
}

// Round 5
// 113.255 us; speedup vs baseline: 1.1528x; 1.1528x over previous
//
#include <hip/hip_runtime.h>
#include <cmath>
#include <complex>
#include <cstring>
#include <algorithm>

typedef float f32x4 __attribute__((ext_vector_type(4)));

// ---------------- CG coefficient pack (computed on host, passed by value) ----

struct CGPack {
  float A0;          // (1,1,1) path 0x0->0
  float B[3][3];     // (1,3,3) -> [j][k]   0x1->1
  float C[5][5];     // (1,5,5) -> [j][k]   0x2->2
  float D[3][3];     // (3,1,3) -> [i][k]   1x0->1
  float E[3][3];     // (3,3,1) -> [i][j]   1x1->0
  float F[3][3][5];  // (3,3,5)             1x1->2
  float G[3][5][3];  // (3,5,3)             1x2->1
  float H[5][5];     // (5,1,5) -> [i][k]   2x0->2
  float I[5][3][3];  // (5,3,3)             2x1->1
  float J[5][5];     // (5,5,1) -> [i][j]   2x2->0
  float K[5][5][5];  // (5,5,5)             2x2->2
};

namespace {

using cd = std::complex<double>;

double factd(int n) { double r = 1.0; for (int i = 2; i <= n; ++i) r *= i; return r; }

double su2_cg(int j1, int m1, int j2, int m2, int j3, int m3) {
  if (m3 != m1 + m2) return 0.0;
  int vmin = std::max(std::max(-j1 + j2 + m3, -j1 + m1), 0);
  int vmax = std::min(std::min(j2 + j3 + m1, j3 - j1 + j2), j3 + m3);
  double C = std::sqrt((2.0 * j3 + 1.0) *
      factd(j3 + j1 - j2) * factd(j3 - j1 + j2) * factd(j1 + j2 - j3) *
      factd(j3 + m3) * factd(j3 - m3) /
      (factd(j1 + j2 + j3 + 1) * factd(j1 - m1) * factd(j1 + m1) *
       factd(j2 - m2) * factd(j2 + m2)));
  double S = 0.0;
  for (int v = vmin; v <= vmax; ++v) {
    double sgn = ((v + j2 + m2) & 1) ? -1.0 : 1.0;
    S += sgn * factd(j2 + j3 + m1 - v) * factd(j1 - m1 + v) /
         (factd(v) * factd(j3 - j1 + j2 - v) * factd(j3 + m3 - v) *
          factd(v + j1 - j2 - m3));
  }
  return C * S;
}

void real_to_complex(int l, cd q[5][5]) {
  for (int r = 0; r < 5; ++r)
    for (int c = 0; c < 5; ++c) q[r][c] = cd(0.0, 0.0);
  const double is2 = 1.0 / std::sqrt(2.0);
  for (int m = -l; m < 0; ++m) {
    q[l + m][l - m] = cd(is2, 0.0);   // col l+|m|
    q[l + m][l + m] = cd(0.0, -is2);  // col l-|m|
  }
  q[l][l] = cd(1.0, 0.0);
  for (int m = 1; m <= l; ++m) {
    double s = (m & 1) ? -1.0 : 1.0;
    q[l + m][l + m] = cd(s * is2, 0.0);
    q[l + m][l - m] = cd(0.0, s * is2);
  }
  cd f(1.0, 0.0);
  const cd mi(0.0, -1.0);
  for (int t = 0; t < l; ++t) f *= mi;
  for (int r = 0; r < 5; ++r)
    for (int c = 0; c < 5; ++c) q[r][c] *= f;
}

// dense real CG with component norm (== reference clebsch_gordan * sqrt(2*l3+1))
void compute_cg(int l1, int l2, int l3, float* out) {
  const int n1 = 2 * l1 + 1, n2 = 2 * l2 + 1, n3 = 2 * l3 + 1;
  double su2[5][5][5] = {};
  if (std::abs(l1 - l2) <= l3 && l3 <= l1 + l2) {
    for (int m1 = -l1; m1 <= l1; ++m1)
      for (int m2 = -l2; m2 <= l2; ++m2)
        if (std::abs(m1 + m2) <= l3)
          su2[l1 + m1][l2 + m2][l3 + m1 + m2] = su2_cg(l1, m1, l2, m2, l3, m1 + m2);
  }
  const double norm = 1.0 / std::sqrt(2.0 * l3 + 1.0);       // from _su2_cg_mat
  const double comp = std::sqrt(2.0 * l3 + 1.0);             // component norm
  cd q1[5][5], q2[5][5], q3[5][5];
  real_to_complex(l1, q1);
  real_to_complex(l2, q2);
  real_to_complex(l3, q3);
  for (int j = 0; j < n1; ++j)
    for (int ll = 0; ll < n2; ++ll)
      for (int m = 0; m < n3; ++m) {
        cd acc(0.0, 0.0);
        for (int i = 0; i < n1; ++i)
          for (int k = 0; k < n2; ++k)
            for (int n = 0; n < n3; ++n)
              acc += q1[i][j] * q2[k][ll] * std::conj(q3[n][m]) * su2[i][k][n];
        out[(j * n2 + ll) * n3 + m] = (float)(acc.real() * norm * comp);
      }
}

CGPack make_pack() {
  CGPack p;
  float t[125];
  compute_cg(0, 0, 0, t); p.A0 = t[0];
  compute_cg(0, 1, 1, t); std::memcpy(p.B, t, 9 * sizeof(float));
  compute_cg(0, 2, 2, t); std::memcpy(p.C, t, 25 * sizeof(float));
  compute_cg(1, 0, 1, t); std::memcpy(p.D, t, 9 * sizeof(float));
  compute_cg(1, 1, 0, t); std::memcpy(p.E, t, 9 * sizeof(float));
  compute_cg(1, 1, 2, t); std::memcpy(p.F, t, 45 * sizeof(float));
  compute_cg(1, 2, 1, t); std::memcpy(p.G, t, 45 * sizeof(float));
  compute_cg(2, 0, 2, t); std::memcpy(p.H, t, 25 * sizeof(float));
  compute_cg(2, 1, 1, t); std::memcpy(p.I, t, 45 * sizeof(float));
  compute_cg(2, 2, 0, t); std::memcpy(p.J, t, 25 * sizeof(float));
  compute_cg(2, 2, 2, t); std::memcpy(p.K, t, 125 * sizeof(float));
  return p;
}

}  // namespace

// ---------------- kernel ------------------------------------------------------
//
// Direct-store design: one thread owns 4 consecutive u-channels of one row.
// lcm(4,3)=12, lcm(4,5)=20 -> every chunk's 4-u slice is f32x4-aligned:
//   w=1 chunks (A,E,J): 1 vec each; w=3 (B,D,G,I): 3 vecs; w=5 (C,F,H,K): 5 vecs.
// Inputs are 9 aligned f32x4 loads. No LDS, no barriers. Plain (temporal)
// stores: each 64B line is fully covered by the same wave within the 3-5
// adjacent store instructions of its chunk, so L2 merges before writeback.
// (NO launch_bounds min-waves: R4 showed forcing 8 waves/EU spills ~30 VGPRs.)

__global__ __launch_bounds__(256) void tp_kernel(
    const float* __restrict__ in1, const float* __restrict__ in2,
    float* __restrict__ out, CGPack cg, int Btot) {
  const int g = blockIdx.x * 256 + threadIdx.x;
  const int r = g >> 5;    // batch row
  const int ub = g & 31;   // u-block: u = 4*ub .. 4*ub+3
  if (r >= Btot) return;

  const float* r1 = in1 + (size_t)r * 1152;
  const float* r2 = in2 + (size_t)r * 9;

  // ---- vectorized input loads
  float x0[4], x1[12], x2[20];
  {
    f32x4 v = *reinterpret_cast<const f32x4*>(r1 + 4 * ub);
#pragma unroll
    for (int e = 0; e < 4; ++e) x0[e] = v[e];
  }
  {
    const f32x4* p = reinterpret_cast<const f32x4*>(r1 + 128 + 12 * ub);
#pragma unroll
    for (int i = 0; i < 3; ++i) {
      f32x4 v = p[i];
#pragma unroll
      for (int e = 0; e < 4; ++e) x1[4 * i + e] = v[e];
    }
  }
  {
    const f32x4* p = reinterpret_cast<const f32x4*>(r1 + 512 + 20 * ub);
#pragma unroll
    for (int i = 0; i < 5; ++i) {
      f32x4 v = p[i];
#pragma unroll
      for (int e = 0; e < 4; ++e) x2[4 * i + e] = v[e];
    }
  }
  const float b0 = r2[0];
  float b1[3], b2[5];
#pragma unroll
  for (int j = 0; j < 3; ++j) b1[j] = r2[1 + j];
#pragma unroll
  for (int j = 0; j < 5; ++j) b2[j] = r2[4 + j];

  float* ro = out + (size_t)r * 4480;

  // ---- width-1 chunks: A (0), E (128), J (256) — one vec store each
  {
    f32x4 o;
#pragma unroll
    for (int du = 0; du < 4; ++du) o[du] = x0[du] * b0 * cg.A0;
    *reinterpret_cast<f32x4*>(ro + 4 * ub) = o;
  }
  {
    f32x4 o;
#pragma unroll
    for (int du = 0; du < 4; ++du) {
      float s = 0.f;
#pragma unroll
      for (int i = 0; i < 3; ++i)
#pragma unroll
        for (int j = 0; j < 3; ++j) s += x1[3 * du + i] * b1[j] * cg.E[i][j];
      o[du] = s;
    }
    *reinterpret_cast<f32x4*>(ro + 128 + 4 * ub) = o;
  }
  {
    f32x4 o;
#pragma unroll
    for (int du = 0; du < 4; ++du) {
      float s = 0.f;
#pragma unroll
      for (int i = 0; i < 5; ++i)
#pragma unroll
        for (int j = 0; j < 5; ++j) s += x2[5 * du + i] * b2[j] * cg.J[i][j];
      o[du] = s;
    }
    *reinterpret_cast<f32x4*>(ro + 256 + 4 * ub) = o;
  }

  // ---- width-3 chunks: B (384), D (768), G (1152), I (1536) — 3 vecs each
  {
    float tmp[12];
#pragma unroll
    for (int du = 0; du < 4; ++du)
#pragma unroll
      for (int k = 0; k < 3; ++k) {
        float s = 0.f;
#pragma unroll
        for (int j = 0; j < 3; ++j) s += b1[j] * cg.B[j][k];
        tmp[3 * du + k] = x0[du] * s;
      }
    f32x4* d = reinterpret_cast<f32x4*>(ro + 384 + 12 * ub);
#pragma unroll
    for (int v = 0; v < 3; ++v) {
      f32x4 w;
#pragma unroll
      for (int e = 0; e < 4; ++e) w[e] = tmp[4 * v + e];
      d[v] = w;
    }
  }
  {
    float tmp[12];
#pragma unroll
    for (int du = 0; du < 4; ++du)
#pragma unroll
      for (int k = 0; k < 3; ++k) {
        float s = 0.f;
#pragma unroll
        for (int i = 0; i < 3; ++i) s += x1[3 * du + i] * cg.D[i][k];
        tmp[3 * du + k] = s * b0;
      }
    f32x4* d = reinterpret_cast<f32x4*>(ro + 768 + 12 * ub);
#pragma unroll
    for (int v = 0; v < 3; ++v) {
      f32x4 w;
#pragma unroll
      for (int e = 0; e < 4; ++e) w[e] = tmp[4 * v + e];
      d[v] = w;
    }
  }
  {
    float tmp[12];
#pragma unroll
    for (int du = 0; du < 4; ++du)
#pragma unroll
      for (int k = 0; k < 3; ++k) {
        float s = 0.f;
#pragma unroll
        for (int i = 0; i < 3; ++i)
#pragma unroll
          for (int j = 0; j < 5; ++j) s += x1[3 * du + i] * b2[j] * cg.G[i][j][k];
        tmp[3 * du + k] = s;
      }
    f32x4* d = reinterpret_cast<f32x4*>(ro + 1152 + 12 * ub);
#pragma unroll
    for (int v = 0; v < 3; ++v) {
      f32x4 w;
#pragma unroll
      for (int e = 0; e < 4; ++e) w[e] = tmp[4 * v + e];
      d[v] = w;
    }
  }
  {
    float tmp[12];
#pragma unroll
    for (int du = 0; du < 4; ++du)
#pragma unroll
      for (int k = 0; k < 3; ++k) {
        float s = 0.f;
#pragma unroll
        for (int i = 0; i < 5; ++i)
#pragma unroll
          for (int j = 0; j < 3; ++j) s += x2[5 * du + i] * b1[j] * cg.I[i][j][k];
        tmp[3 * du + k] = s;
      }
    f32x4* d = reinterpret_cast<f32x4*>(ro + 1536 + 12 * ub);
#pragma unroll
    for (int v = 0; v < 3; ++v) {
      f32x4 w;
#pragma unroll
      for (int e = 0; e < 4; ++e) w[e] = tmp[4 * v + e];
      d[v] = w;
    }
  }

  // ---- width-5 chunks: C (1920), F (2560), H (3200), K (3840) — 5 vecs each
  {
    float tmp[20];
#pragma unroll
    for (int du = 0; du < 4; ++du)
#pragma unroll
      for (int k = 0; k < 5; ++k) {
        float s = 0.f;
#pragma unroll
        for (int j = 0; j < 5; ++j) s += b2[j] * cg.C[j][k];
        tmp[5 * du + k] = x0[du] * s;
      }
    f32x4* d = reinterpret_cast<f32x4*>(ro + 1920 + 20 * ub);
#pragma unroll
    for (int v = 0; v < 5; ++v) {
      f32x4 w;
#pragma unroll
      for (int e = 0; e < 4; ++e) w[e] = tmp[4 * v + e];
      d[v] = w;
    }
  }
  {
    float tmp[20];
#pragma unroll
    for (int du = 0; du < 4; ++du)
#pragma unroll
      for (int k = 0; k < 5; ++k) {
        float s = 0.f;
#pragma unroll
        for (int i = 0; i < 3; ++i)
#pragma unroll
          for (int j = 0; j < 3; ++j) s += x1[3 * du + i] * b1[j] * cg.F[i][j][k];
        tmp[5 * du + k] = s;
      }
    f32x4* d = reinterpret_cast<f32x4*>(ro + 2560 + 20 * ub);
#pragma unroll
    for (int v = 0; v < 5; ++v) {
      f32x4 w;
#pragma unroll
      for (int e = 0; e < 4; ++e) w[e] = tmp[4 * v + e];
      d[v] = w;
    }
  }
  {
    float tmp[20];
#pragma unroll
    for (int du = 0; du < 4; ++du)
#pragma unroll
      for (int k = 0; k < 5; ++k) {
        float s = 0.f;
#pragma unroll
        for (int i = 0; i < 5; ++i) s += x2[5 * du + i] * cg.H[i][k];
        tmp[5 * du + k] = s * b0;
      }
    f32x4* d = reinterpret_cast<f32x4*>(ro + 3200 + 20 * ub);
#pragma unroll
    for (int v = 0; v < 5; ++v) {
      f32x4 w;
#pragma unroll
      for (int e = 0; e < 4; ++e) w[e] = tmp[4 * v + e];
      d[v] = w;
    }
  }
  {
    float tmp[20];
#pragma unroll
    for (int du = 0; du < 4; ++du)
#pragma unroll
      for (int k = 0; k < 5; ++k) {
        float s = 0.f;
#pragma unroll
        for (int i = 0; i < 5; ++i)
#pragma unroll
          for (int j = 0; j < 5; ++j) s += x2[5 * du + i] * b2[j] * cg.K[i][j][k];
        tmp[5 * du + k] = s;
      }
    f32x4* d = reinterpret_cast<f32x4*>(ro + 3840 + 20 * ub);
#pragma unroll
    for (int v = 0; v < 5; ++v) {
      f32x4 w;
#pragma unroll
      for (int e = 0; e < 4; ++e) w[e] = tmp[4 * v + e];
      d[v] = w;
    }
  }
}

// ---------------- launch ------------------------------------------------------

extern "C" void kernel_launch(void* const* d_in, const int* in_sizes, int n_in,
                              void* d_out, int out_size, void* d_ws, size_t ws_size,
                              hipStream_t stream) {
  const float* in1 = (const float*)d_in[0];
  const float* in2 = (const float*)d_in[1];
  float* out = (float*)d_out;

  const CGPack pack = make_pack();  // pure host math, deterministic, capture-safe

  const int B = in_sizes[0] / 1152;  // 16384
  const long long total = (long long)B * 32;  // 32 threads per row
  const int blocks = (int)((total + 255) / 256);

  hipLaunchKernelGGL(tp_kernel, dim3(blocks), dim3(256), 0, stream,
                     in1, in2, out, pack, B);
}

// Round 6
// 83.364 us; speedup vs baseline: 1.5661x; 1.3586x over previous
//
#include <hip/hip_runtime.h>
#include <cmath>
#include <complex>
#include <cstring>
#include <algorithm>

typedef float f32x4 __attribute__((ext_vector_type(4)));

// ---------------- CG coefficient pack (computed on host, passed by value) ----

struct CGPack {
  float A0;          // (1,1,1) path 0x0->0
  float B[3][3];     // (1,3,3) -> [j][k]   0x1->1
  float C[5][5];     // (1,5,5) -> [j][k]   0x2->2
  float D[3][3];     // (3,1,3) -> [i][k]   1x0->1
  float E[3][3];     // (3,3,1) -> [i][j]   1x1->0
  float F[3][3][5];  // (3,3,5)             1x1->2
  float G[3][5][3];  // (3,5,3)             1x2->1
  float H[5][5];     // (5,1,5) -> [i][k]   2x0->2
  float I[5][3][3];  // (5,3,3)             2x1->1
  float J[5][5];     // (5,5,1) -> [i][j]   2x2->0
  float K[5][5][5];  // (5,5,5)             2x2->2
};

namespace {

using cd = std::complex<double>;

double factd(int n) { double r = 1.0; for (int i = 2; i <= n; ++i) r *= i; return r; }

double su2_cg(int j1, int m1, int j2, int m2, int j3, int m3) {
  if (m3 != m1 + m2) return 0.0;
  int vmin = std::max(std::max(-j1 + j2 + m3, -j1 + m1), 0);
  int vmax = std::min(std::min(j2 + j3 + m1, j3 - j1 + j2), j3 + m3);
  double C = std::sqrt((2.0 * j3 + 1.0) *
      factd(j3 + j1 - j2) * factd(j3 - j1 + j2) * factd(j1 + j2 - j3) *
      factd(j3 + m3) * factd(j3 - m3) /
      (factd(j1 + j2 + j3 + 1) * factd(j1 - m1) * factd(j1 + m1) *
       factd(j2 - m2) * factd(j2 + m2)));
  double S = 0.0;
  for (int v = vmin; v <= vmax; ++v) {
    double sgn = ((v + j2 + m2) & 1) ? -1.0 : 1.0;
    S += sgn * factd(j2 + j3 + m1 - v) * factd(j1 - m1 + v) /
         (factd(v) * factd(j3 - j1 + j2 - v) * factd(j3 + m3 - v) *
          factd(v + j1 - j2 - m3));
  }
  return C * S;
}

void real_to_complex(int l, cd q[5][5]) {
  for (int r = 0; r < 5; ++r)
    for (int c = 0; c < 5; ++c) q[r][c] = cd(0.0, 0.0);
  const double is2 = 1.0 / std::sqrt(2.0);
  for (int m = -l; m < 0; ++m) {
    q[l + m][l - m] = cd(is2, 0.0);   // col l+|m|
    q[l + m][l + m] = cd(0.0, -is2);  // col l-|m|
  }
  q[l][l] = cd(1.0, 0.0);
  for (int m = 1; m <= l; ++m) {
    double s = (m & 1) ? -1.0 : 1.0;
    q[l + m][l + m] = cd(s * is2, 0.0);
    q[l + m][l - m] = cd(0.0, s * is2);
  }
  cd f(1.0, 0.0);
  const cd mi(0.0, -1.0);
  for (int t = 0; t < l; ++t) f *= mi;
  for (int r = 0; r < 5; ++r)
    for (int c = 0; c < 5; ++c) q[r][c] *= f;
}

// dense real CG with component norm (== reference clebsch_gordan * sqrt(2*l3+1))
void compute_cg(int l1, int l2, int l3, float* out) {
  const int n1 = 2 * l1 + 1, n2 = 2 * l2 + 1, n3 = 2 * l3 + 1;
  double su2[5][5][5] = {};
  if (std::abs(l1 - l2) <= l3 && l3 <= l1 + l2) {
    for (int m1 = -l1; m1 <= l1; ++m1)
      for (int m2 = -l2; m2 <= l2; ++m2)
        if (std::abs(m1 + m2) <= l3)
          su2[l1 + m1][l2 + m2][l3 + m1 + m2] = su2_cg(l1, m1, l2, m2, l3, m1 + m2);
  }
  const double norm = 1.0 / std::sqrt(2.0 * l3 + 1.0);       // from _su2_cg_mat
  const double comp = std::sqrt(2.0 * l3 + 1.0);             // component norm
  cd q1[5][5], q2[5][5], q3[5][5];
  real_to_complex(l1, q1);
  real_to_complex(l2, q2);
  real_to_complex(l3, q3);
  for (int j = 0; j < n1; ++j)
    for (int ll = 0; ll < n2; ++ll)
      for (int m = 0; m < n3; ++m) {
        cd acc(0.0, 0.0);
        for (int i = 0; i < n1; ++i)
          for (int k = 0; k < n2; ++k)
            for (int n = 0; n < n3; ++n)
              acc += q1[i][j] * q2[k][ll] * std::conj(q3[n][m]) * su2[i][k][n];
        out[(j * n2 + ll) * n3 + m] = (float)(acc.real() * norm * comp);
      }
}

CGPack make_pack() {
  CGPack p;
  float t[125];
  compute_cg(0, 0, 0, t); p.A0 = t[0];
  compute_cg(0, 1, 1, t); std::memcpy(p.B, t, 9 * sizeof(float));
  compute_cg(0, 2, 2, t); std::memcpy(p.C, t, 25 * sizeof(float));
  compute_cg(1, 0, 1, t); std::memcpy(p.D, t, 9 * sizeof(float));
  compute_cg(1, 1, 0, t); std::memcpy(p.E, t, 9 * sizeof(float));
  compute_cg(1, 1, 2, t); std::memcpy(p.F, t, 45 * sizeof(float));
  compute_cg(1, 2, 1, t); std::memcpy(p.G, t, 45 * sizeof(float));
  compute_cg(2, 0, 2, t); std::memcpy(p.H, t, 25 * sizeof(float));
  compute_cg(2, 1, 1, t); std::memcpy(p.I, t, 45 * sizeof(float));
  compute_cg(2, 2, 0, t); std::memcpy(p.J, t, 25 * sizeof(float));
  compute_cg(2, 2, 2, t); std::memcpy(p.K, t, 125 * sizeof(float));
  return p;
}

}  // namespace

// ---------------- kernel ------------------------------------------------------
//
// Block = 256 threads = 2 batch rows (128 u-channels each).
// Phase-split LDS out-stage (same region reused):
//   phase A: l3 in {0,1} -> 1920 floats/row;  phase B: l3 == 2 -> 2560/row.
// LDS = 2*2560*4 = 20480 B. launch_bounds(256,6) -> VGPR cap ~85 (live set
// ~65, no spill; R4's (256,8)=64-cap spilled ~30 VGPRs and doubled runtime).
// Phase-B accumulation (pure VALU from regs) is placed between the storeA
// loop and the next barrier so storeA's write-acks drain under it.

__global__ __launch_bounds__(256, 6) void tp_kernel(
    const float* __restrict__ in1, const float* __restrict__ in2,
    float* __restrict__ out, CGPack cg, int Btot) {
  __shared__ float smem[5120];  // 2 rows x 2560 (phase B size; phase A uses 2x1920)

  const int t = threadIdx.x;
  const int row = t >> 7;   // 0 or 1
  const int u = t & 127;
  const long long b = (long long)blockIdx.x * 2 + row;
  const bool live = (b < Btot);

  float a0 = 0.f, b0 = 0.f;
  float a1[3] = {}, a2[5] = {}, b1[3] = {}, b2[5] = {};

  if (live) {
    const float* r1 = in1 + (size_t)b * 1152;
    const float* r2 = in2 + (size_t)b * 9;
    a0 = r1[u];
#pragma unroll
    for (int i = 0; i < 3; ++i) a1[i] = r1[128 + 3 * u + i];
#pragma unroll
    for (int i = 0; i < 5; ++i) a2[i] = r1[512 + 5 * u + i];
    b0 = r2[0];
#pragma unroll
    for (int j = 0; j < 3; ++j) b1[j] = r2[1 + j];
#pragma unroll
    for (int j = 0; j < 5; ++j) b2[j] = r2[4 + j];
  }

  const long long rows_left = (long long)Btot - (long long)blockIdx.x * 2;
  const int nrows = rows_left >= 2 ? 2 : (rows_left == 1 ? 1 : 0);
  float* const orow0 = out + (size_t)blockIdx.x * 2 * 4480;

  // ================= phase A compute: l3 = 0 and l3 = 1 =================
  {
    float* so = smem + row * 1920;

    float oA = a0 * b0 * cg.A0;
    float oE = 0.f, oJ = 0.f;
#pragma unroll
    for (int i = 0; i < 3; ++i)
#pragma unroll
      for (int j = 0; j < 3; ++j) oE += a1[i] * b1[j] * cg.E[i][j];
#pragma unroll
    for (int i = 0; i < 5; ++i)
#pragma unroll
      for (int j = 0; j < 5; ++j) oJ += a2[i] * b2[j] * cg.J[i][j];

    float oB[3] = {}, oD[3] = {}, oG[3] = {}, oI[3] = {};
#pragma unroll
    for (int j = 0; j < 3; ++j)
#pragma unroll
      for (int k = 0; k < 3; ++k) oB[k] += a0 * b1[j] * cg.B[j][k];
#pragma unroll
    for (int i = 0; i < 3; ++i)
#pragma unroll
      for (int k = 0; k < 3; ++k) oD[k] += a1[i] * b0 * cg.D[i][k];
#pragma unroll
    for (int i = 0; i < 3; ++i)
#pragma unroll
      for (int j = 0; j < 5; ++j) {
        const float p = a1[i] * b2[j];
#pragma unroll
        for (int k = 0; k < 3; ++k) oG[k] += p * cg.G[i][j][k];
      }
#pragma unroll
    for (int i = 0; i < 5; ++i)
#pragma unroll
      for (int j = 0; j < 3; ++j) {
        const float p = a2[i] * b1[j];
#pragma unroll
        for (int k = 0; k < 3; ++k) oI[k] += p * cg.I[i][j][k];
      }

    so[u] = oA;
    so[128 + u] = oE;
    so[256 + u] = oJ;
#pragma unroll
    for (int k = 0; k < 3; ++k) {
      so[384 + 3 * u + k] = oB[k];
      so[768 + 3 * u + k] = oD[k];
      so[1152 + 3 * u + k] = oG[k];
      so[1536 + 3 * u + k] = oI[k];
    }
  }

  __syncthreads();  // A in LDS

  // ---- store phase A: per-row contiguous 480 f32x4, nt
  {
    const int nvec = nrows * 480;
    for (int i = t; i < nvec; i += 256) {
      const int r = (i >= 480);
      const int idx = i - r * 480;
      const f32x4 v = reinterpret_cast<const f32x4*>(smem + r * 1920)[idx];
      f32x4* dst = reinterpret_cast<f32x4*>(orow0 + (size_t)r * 4480);
      __builtin_nontemporal_store(v, dst + idx);
    }
  }

  // ================= phase B compute (regs only; runs under storeA drain) ====
  float oC[5] = {}, oF[5] = {}, oH[5] = {}, oK[5] = {};
#pragma unroll
  for (int j = 0; j < 5; ++j)
#pragma unroll
    for (int k = 0; k < 5; ++k) oC[k] += a0 * b2[j] * cg.C[j][k];
#pragma unroll
  for (int i = 0; i < 3; ++i)
#pragma unroll
    for (int j = 0; j < 3; ++j) {
      const float p = a1[i] * b1[j];
#pragma unroll
      for (int k = 0; k < 5; ++k) oF[k] += p * cg.F[i][j][k];
    }
#pragma unroll
  for (int i = 0; i < 5; ++i)
#pragma unroll
    for (int k = 0; k < 5; ++k) oH[k] += a2[i] * b0 * cg.H[i][k];
#pragma unroll
  for (int i = 0; i < 5; ++i)
#pragma unroll
    for (int j = 0; j < 5; ++j) {
      const float p = a2[i] * b2[j];
#pragma unroll
      for (int k = 0; k < 5; ++k) oK[k] += p * cg.K[i][j][k];
    }

  __syncthreads();  // storeA's LDS reads done -> safe to overwrite smem

  {
    float* so = smem + row * 2560;
#pragma unroll
    for (int k = 0; k < 5; ++k) {
      so[5 * u + k] = oC[k];
      so[640 + 5 * u + k] = oF[k];
      so[1280 + 5 * u + k] = oH[k];
      so[1920 + 5 * u + k] = oK[k];
    }
  }

  __syncthreads();  // B in LDS

  // ---- store phase B: per-row contiguous 640 f32x4 at row offset 1920, nt
  {
    const int nvec = nrows * 640;
    for (int i = t; i < nvec; i += 256) {
      const int r = (i >= 640);
      const int idx = i - r * 640;
      const f32x4 v = reinterpret_cast<const f32x4*>(smem + r * 2560)[idx];
      f32x4* dst = reinterpret_cast<f32x4*>(orow0 + (size_t)r * 4480 + 1920);
      __builtin_nontemporal_store(v, dst + idx);
    }
  }
}

// ---------------- launch ------------------------------------------------------

extern "C" void kernel_launch(void* const* d_in, const int* in_sizes, int n_in,
                              void* d_out, int out_size, void* d_ws, size_t ws_size,
                              hipStream_t stream) {
  const float* in1 = (const float*)d_in[0];
  const float* in2 = (const float*)d_in[1];
  float* out = (float*)d_out;

  const CGPack pack = make_pack();  // pure host math, deterministic, capture-safe

  const int B = in_sizes[0] / 1152;  // 16384
  const int blocks = (B + 1) / 2;

  hipLaunchKernelGGL(tp_kernel, dim3(blocks), dim3(256), 0, stream,
                     in1, in2, out, pack, B);
}

// Round 7
// 63.055 us; speedup vs baseline: 2.0706x; 1.3221x over previous
//
#include <hip/hip_runtime.h>
#include <cmath>
#include <complex>
#include <cstring>
#include <algorithm>

typedef float f32x4 __attribute__((ext_vector_type(4)));

// ---------------- CG coefficient pack (computed on host, passed by value) ----

struct CGPack {
  float A0;          // (1,1,1) path 0x0->0
  float B[3][3];     // (1,3,3) -> [j][k]   0x1->1
  float C[5][5];     // (1,5,5) -> [j][k]   0x2->2
  float D[3][3];     // (3,1,3) -> [i][k]   1x0->1
  float E[3][3];     // (3,3,1) -> [i][j]   1x1->0
  float F[3][3][5];  // (3,3,5)             1x1->2
  float G[3][5][3];  // (3,5,3)             1x2->1
  float H[5][5];     // (5,1,5) -> [i][k]   2x0->2
  float I[5][3][3];  // (5,3,3)             2x1->1
  float J[5][5];     // (5,5,1) -> [i][j]   2x2->0
  float K[5][5][5];  // (5,5,5)             2x2->2
};

namespace {

using cd = std::complex<double>;

double factd(int n) { double r = 1.0; for (int i = 2; i <= n; ++i) r *= i; return r; }

double su2_cg(int j1, int m1, int j2, int m2, int j3, int m3) {
  if (m3 != m1 + m2) return 0.0;
  int vmin = std::max(std::max(-j1 + j2 + m3, -j1 + m1), 0);
  int vmax = std::min(std::min(j2 + j3 + m1, j3 - j1 + j2), j3 + m3);
  double C = std::sqrt((2.0 * j3 + 1.0) *
      factd(j3 + j1 - j2) * factd(j3 - j1 + j2) * factd(j1 + j2 - j3) *
      factd(j3 + m3) * factd(j3 - m3) /
      (factd(j1 + j2 + j3 + 1) * factd(j1 - m1) * factd(j1 + m1) *
       factd(j2 - m2) * factd(j2 + m2)));
  double S = 0.0;
  for (int v = vmin; v <= vmax; ++v) {
    double sgn = ((v + j2 + m2) & 1) ? -1.0 : 1.0;
    S += sgn * factd(j2 + j3 + m1 - v) * factd(j1 - m1 + v) /
         (factd(v) * factd(j3 - j1 + j2 - v) * factd(j3 + m3 - v) *
          factd(v + j1 - j2 - m3));
  }
  return C * S;
}

void real_to_complex(int l, cd q[5][5]) {
  for (int r = 0; r < 5; ++r)
    for (int c = 0; c < 5; ++c) q[r][c] = cd(0.0, 0.0);
  const double is2 = 1.0 / std::sqrt(2.0);
  for (int m = -l; m < 0; ++m) {
    q[l + m][l - m] = cd(is2, 0.0);   // col l+|m|
    q[l + m][l + m] = cd(0.0, -is2);  // col l-|m|
  }
  q[l][l] = cd(1.0, 0.0);
  for (int m = 1; m <= l; ++m) {
    double s = (m & 1) ? -1.0 : 1.0;
    q[l + m][l + m] = cd(s * is2, 0.0);
    q[l + m][l - m] = cd(0.0, s * is2);
  }
  cd f(1.0, 0.0);
  const cd mi(0.0, -1.0);
  for (int t = 0; t < l; ++t) f *= mi;
  for (int r = 0; r < 5; ++r)
    for (int c = 0; c < 5; ++c) q[r][c] *= f;
}

// dense real CG with component norm (== reference clebsch_gordan * sqrt(2*l3+1))
void compute_cg(int l1, int l2, int l3, float* out) {
  const int n1 = 2 * l1 + 1, n2 = 2 * l2 + 1, n3 = 2 * l3 + 1;
  double su2[5][5][5] = {};
  if (std::abs(l1 - l2) <= l3 && l3 <= l1 + l2) {
    for (int m1 = -l1; m1 <= l1; ++m1)
      for (int m2 = -l2; m2 <= l2; ++m2)
        if (std::abs(m1 + m2) <= l3)
          su2[l1 + m1][l2 + m2][l3 + m1 + m2] = su2_cg(l1, m1, l2, m2, l3, m1 + m2);
  }
  const double norm = 1.0 / std::sqrt(2.0 * l3 + 1.0);       // from _su2_cg_mat
  const double comp = std::sqrt(2.0 * l3 + 1.0);             // component norm
  cd q1[5][5], q2[5][5], q3[5][5];
  real_to_complex(l1, q1);
  real_to_complex(l2, q2);
  real_to_complex(l3, q3);
  for (int j = 0; j < n1; ++j)
    for (int ll = 0; ll < n2; ++ll)
      for (int m = 0; m < n3; ++m) {
        cd acc(0.0, 0.0);
        for (int i = 0; i < n1; ++i)
          for (int k = 0; k < n2; ++k)
            for (int n = 0; n < n3; ++n)
              acc += q1[i][j] * q2[k][ll] * std::conj(q3[n][m]) * su2[i][k][n];
        out[(j * n2 + ll) * n3 + m] = (float)(acc.real() * norm * comp);
      }
}

CGPack make_pack() {
  CGPack p;
  float t[125];
  compute_cg(0, 0, 0, t); p.A0 = t[0];
  compute_cg(0, 1, 1, t); std::memcpy(p.B, t, 9 * sizeof(float));
  compute_cg(0, 2, 2, t); std::memcpy(p.C, t, 25 * sizeof(float));
  compute_cg(1, 0, 1, t); std::memcpy(p.D, t, 9 * sizeof(float));
  compute_cg(1, 1, 0, t); std::memcpy(p.E, t, 9 * sizeof(float));
  compute_cg(1, 1, 2, t); std::memcpy(p.F, t, 45 * sizeof(float));
  compute_cg(1, 2, 1, t); std::memcpy(p.G, t, 45 * sizeof(float));
  compute_cg(2, 0, 2, t); std::memcpy(p.H, t, 25 * sizeof(float));
  compute_cg(2, 1, 1, t); std::memcpy(p.I, t, 45 * sizeof(float));
  compute_cg(2, 2, 0, t); std::memcpy(p.J, t, 25 * sizeof(float));
  compute_cg(2, 2, 2, t); std::memcpy(p.K, t, 125 * sizeof(float));
  return p;
}

}  // namespace

// ---------------- kernel ------------------------------------------------------
//
// Block = 256 threads = 2 batch rows (128 u-channels each).
// Phase-split LDS out-stage (same region reused):
//   phase A: l3 in {0,1} -> 1920 floats/row;  phase B: l3 == 2 -> 2560/row.
// LDS = 2*2560*4 = 20480 B -> 5-6 blocks/CU at ~96 VGPR (vs R3's 4 at 35.8KB).
// NO min-waves launch bound: R4's (256,8)=64-VGPR cap spilled ~30 regs
// (+67us); R6's (256,6)=85-cap spilled ~10 regs (+20us). Spill cost >>
// occupancy gain every time. Let the allocator take what it needs.
// Phase-B accumulation (pure VALU from regs) sits between storeA and the
// next barrier so storeA's write-acks drain under it.

__global__ __launch_bounds__(256) void tp_kernel(
    const float* __restrict__ in1, const float* __restrict__ in2,
    float* __restrict__ out, CGPack cg, int Btot) {
  __shared__ float smem[5120];  // 2 rows x 2560 (phase B size; phase A uses 2x1920)

  const int t = threadIdx.x;
  const int row = t >> 7;   // 0 or 1
  const int u = t & 127;
  const long long b = (long long)blockIdx.x * 2 + row;
  const bool live = (b < Btot);

  float a0 = 0.f, b0 = 0.f;
  float a1[3] = {}, a2[5] = {}, b1[3] = {}, b2[5] = {};

  if (live) {
    const float* r1 = in1 + (size_t)b * 1152;
    const float* r2 = in2 + (size_t)b * 9;
    a0 = r1[u];
#pragma unroll
    for (int i = 0; i < 3; ++i) a1[i] = r1[128 + 3 * u + i];
#pragma unroll
    for (int i = 0; i < 5; ++i) a2[i] = r1[512 + 5 * u + i];
    b0 = r2[0];
#pragma unroll
    for (int j = 0; j < 3; ++j) b1[j] = r2[1 + j];
#pragma unroll
    for (int j = 0; j < 5; ++j) b2[j] = r2[4 + j];
  }

  const long long rows_left = (long long)Btot - (long long)blockIdx.x * 2;
  const int nrows = rows_left >= 2 ? 2 : (rows_left == 1 ? 1 : 0);
  float* const orow0 = out + (size_t)blockIdx.x * 2 * 4480;

  // ================= phase A compute: l3 = 0 and l3 = 1 =================
  {
    float* so = smem + row * 1920;

    float oA = a0 * b0 * cg.A0;
    float oE = 0.f, oJ = 0.f;
#pragma unroll
    for (int i = 0; i < 3; ++i)
#pragma unroll
      for (int j = 0; j < 3; ++j) oE += a1[i] * b1[j] * cg.E[i][j];
#pragma unroll
    for (int i = 0; i < 5; ++i)
#pragma unroll
      for (int j = 0; j < 5; ++j) oJ += a2[i] * b2[j] * cg.J[i][j];

    float oB[3] = {}, oD[3] = {}, oG[3] = {}, oI[3] = {};
#pragma unroll
    for (int j = 0; j < 3; ++j)
#pragma unroll
      for (int k = 0; k < 3; ++k) oB[k] += a0 * b1[j] * cg.B[j][k];
#pragma unroll
    for (int i = 0; i < 3; ++i)
#pragma unroll
      for (int k = 0; k < 3; ++k) oD[k] += a1[i] * b0 * cg.D[i][k];
#pragma unroll
    for (int i = 0; i < 3; ++i)
#pragma unroll
      for (int j = 0; j < 5; ++j) {
        const float p = a1[i] * b2[j];
#pragma unroll
        for (int k = 0; k < 3; ++k) oG[k] += p * cg.G[i][j][k];
      }
#pragma unroll
    for (int i = 0; i < 5; ++i)
#pragma unroll
      for (int j = 0; j < 3; ++j) {
        const float p = a2[i] * b1[j];
#pragma unroll
        for (int k = 0; k < 3; ++k) oI[k] += p * cg.I[i][j][k];
      }

    so[u] = oA;
    so[128 + u] = oE;
    so[256 + u] = oJ;
#pragma unroll
    for (int k = 0; k < 3; ++k) {
      so[384 + 3 * u + k] = oB[k];
      so[768 + 3 * u + k] = oD[k];
      so[1152 + 3 * u + k] = oG[k];
      so[1536 + 3 * u + k] = oI[k];
    }
  }

  __syncthreads();  // A in LDS

  // ---- store phase A: per-row contiguous 480 f32x4, nt
  {
    const int nvec = nrows * 480;
    for (int i = t; i < nvec; i += 256) {
      const int r = (i >= 480);
      const int idx = i - r * 480;
      const f32x4 v = reinterpret_cast<const f32x4*>(smem + r * 1920)[idx];
      f32x4* dst = reinterpret_cast<f32x4*>(orow0 + (size_t)r * 4480);
      __builtin_nontemporal_store(v, dst + idx);
    }
  }

  // ================= phase B compute (regs only; runs under storeA drain) ====
  float oC[5] = {}, oF[5] = {}, oH[5] = {}, oK[5] = {};
#pragma unroll
  for (int j = 0; j < 5; ++j)
#pragma unroll
    for (int k = 0; k < 5; ++k) oC[k] += a0 * b2[j] * cg.C[j][k];
#pragma unroll
  for (int i = 0; i < 3; ++i)
#pragma unroll
    for (int j = 0; j < 3; ++j) {
      const float p = a1[i] * b1[j];
#pragma unroll
      for (int k = 0; k < 5; ++k) oF[k] += p * cg.F[i][j][k];
    }
#pragma unroll
  for (int i = 0; i < 5; ++i)
#pragma unroll
    for (int k = 0; k < 5; ++k) oH[k] += a2[i] * b0 * cg.H[i][k];
#pragma unroll
  for (int i = 0; i < 5; ++i)
#pragma unroll
    for (int j = 0; j < 5; ++j) {
      const float p = a2[i] * b2[j];
#pragma unroll
      for (int k = 0; k < 5; ++k) oK[k] += p * cg.K[i][j][k];
    }

  __syncthreads();  // storeA's LDS reads done -> safe to overwrite smem

  {
    float* so = smem + row * 2560;
#pragma unroll
    for (int k = 0; k < 5; ++k) {
      so[5 * u + k] = oC[k];
      so[640 + 5 * u + k] = oF[k];
      so[1280 + 5 * u + k] = oH[k];
      so[1920 + 5 * u + k] = oK[k];
    }
  }

  __syncthreads();  // B in LDS

  // ---- store phase B: per-row contiguous 640 f32x4 at row offset 1920, nt
  {
    const int nvec = nrows * 640;
    for (int i = t; i < nvec; i += 256) {
      const int r = (i >= 640);
      const int idx = i - r * 640;
      const f32x4 v = reinterpret_cast<const f32x4*>(smem + r * 2560)[idx];
      f32x4* dst = reinterpret_cast<f32x4*>(orow0 + (size_t)r * 4480 + 1920);
      __builtin_nontemporal_store(v, dst + idx);
    }
  }
}

// ---------------- launch ------------------------------------------------------

extern "C" void kernel_launch(void* const* d_in, const int* in_sizes, int n_in,
                              void* d_out, int out_size, void* d_ws, size_t ws_size,
                              hipStream_t stream) {
  const float* in1 = (const float*)d_in[0];
  const float* in2 = (const float*)d_in[1];
  float* out = (float*)d_out;

  const CGPack pack = make_pack();  // pure host math, deterministic, capture-safe

  const int B = in_sizes[0] / 1152;  // 16384
  const int blocks = (B + 1) / 2;

  hipLaunchKernelGGL(tp_kernel, dim3(blocks), dim3(256), 0, stream,
                     in1, in2, out, pack, B);
}